// Round 3
// baseline (400.983 us; speedup 1.0000x reference)
//
#include <hip/hip_runtime.h>
#include <hip/hip_bf16.h>

typedef __attribute__((ext_vector_type(8))) short bf8_t;          // 8 x bf16
typedef __attribute__((ext_vector_type(4))) float f32x4;
typedef __attribute__((ext_vector_type(4))) unsigned short u16x4;
typedef __attribute__((ext_vector_type(8))) unsigned short u16x8;
typedef unsigned long long ull;

#define DEVI static __device__ __forceinline__

DEVI unsigned short f2bf(float f) {
  union { __hip_bfloat16 h; unsigned short u; } cv;
  cv.h = __float2bfloat16(f);
  return cv.u;
}
DEVI float bf2f(unsigned short u) {
  union { __hip_bfloat16 h; unsigned short u; } cv;
  cv.u = u;
  return __bfloat162float(cv.h);
}

// ---------------- fp32 -> bf16 convert ----------------
__global__ void cvt_kernel(const float* __restrict__ src, unsigned short* __restrict__ dst, int n4) {
  int i = blockIdx.x * blockDim.x + threadIdx.x;
  if (i >= n4) return;
  float4 v = reinterpret_cast<const float4*>(src)[i];
  u16x4 o;
  o[0] = f2bf(v.x); o[1] = f2bf(v.y); o[2] = f2bf(v.z); o[3] = f2bf(v.w);
  reinterpret_cast<u16x4*>(dst)[i] = o;
}

// ---------------- mask fp32 -> bitmask via ballot ----------------
// bits[row][4*W + e] bit p  <->  mask[row][256*W + 4*p + e]
__global__ __launch_bounds__(256) void maskpack_kernel(const float* __restrict__ mask,
                                                       ull* __restrict__ bits) {
  const int w = threadIdx.x >> 6, L = threadIdx.x & 63;
  const long long row = (long long)blockIdx.x * 4 + w;
  const float* mp = mask + row * 1024 + 4 * L;
  ull* bout = bits + row * 16;
#pragma unroll
  for (int p = 0; p < 4; ++p) {
    float4 v = *reinterpret_cast<const float4*>(mp + 256 * p);
    ull b0 = __ballot(v.x != 0.f);
    ull b1 = __ballot(v.y != 0.f);
    ull b2 = __ballot(v.z != 0.f);
    ull b3 = __ballot(v.w != 0.f);
    if (L == 0) {
      bout[4 * p + 0] = b0; bout[4 * p + 1] = b1;
      bout[4 * p + 2] = b2; bout[4 * p + 3] = b3;
    }
  }
}

// ---------------- QKV projection GEMM; also emits normalized qn/kn ----------------
__global__ __launch_bounds__(256) void qkv_gemm_kernel(
    const unsigned short* __restrict__ x_bf,
    const unsigned short* __restrict__ wq_bf, const unsigned short* __restrict__ wk_bf,
    const unsigned short* __restrict__ wv_bf,
    const float* __restrict__ bq, const float* __restrict__ bk, const float* __restrict__ bv,
    unsigned short* __restrict__ q_bf, unsigned short* __restrict__ k_bf,
    unsigned short* __restrict__ v_bf,
    unsigned short* __restrict__ qn_bf, unsigned short* __restrict__ kn_bf)
{
  const int m0 = blockIdx.x * 64;
  const int nt = blockIdx.y;
  const int p = nt >> 3, h = nt & 7, n0 = h * 64;
  const unsigned short* W = (p == 0) ? wq_bf : (p == 1) ? wk_bf : wv_bf;
  const float* bias = (p == 0) ? bq : (p == 1) ? bk : bv;
  unsigned short* dst = (p == 0) ? q_bf : (p == 1) ? k_bf : v_bf;
  const int w = threadIdx.x >> 6, L = threadIdx.x & 63, c = L & 15, g = L >> 4;
  const unsigned short* arow = x_bf + (long long)(m0 + 16 * w + c) * 512 + 8 * g;
  const unsigned short* wrow = W + (long long)(n0 + c) * 512 + 8 * g;
  f32x4 acc0 = {0.f, 0.f, 0.f, 0.f}, acc1 = acc0, acc2 = acc0, acc3 = acc0;
#pragma unroll 4
  for (int kk = 0; kk < 16; ++kk) {
    bf8_t a  = *reinterpret_cast<const bf8_t*>(arow + 32 * kk);
    bf8_t b0 = *reinterpret_cast<const bf8_t*>(wrow + 32 * kk);
    bf8_t b1 = *reinterpret_cast<const bf8_t*>(wrow + 16 * 512 + 32 * kk);
    bf8_t b2 = *reinterpret_cast<const bf8_t*>(wrow + 32 * 512 + 32 * kk);
    bf8_t b3 = *reinterpret_cast<const bf8_t*>(wrow + 48 * 512 + 32 * kk);
    acc0 = __builtin_amdgcn_mfma_f32_16x16x32_bf16(a, b0, acc0, 0, 0, 0);
    acc1 = __builtin_amdgcn_mfma_f32_16x16x32_bf16(a, b1, acc1, 0, 0, 0);
    acc2 = __builtin_amdgcn_mfma_f32_16x16x32_bf16(a, b2, acc2, 0, 0, 0);
    acc3 = __builtin_amdgcn_mfma_f32_16x16x32_bf16(a, b3, acc3, 0, 0, 0);
  }
  f32x4 accs[4] = {acc0, acc1, acc2, acc3};
  unsigned short ub[4][4];
  float nacc[4] = {0.f, 0.f, 0.f, 0.f};
#pragma unroll
  for (int t = 0; t < 4; ++t) {
    float bvt = bias[n0 + 16 * t + c];
#pragma unroll
    for (int r = 0; r < 4; ++r) {
      ub[t][r] = f2bf(accs[t][r] + bvt);
      float v = bf2f(ub[t][r]);
      nacc[r] += v * v;
    }
  }
  float irn[4];
  if (p < 2) {
#pragma unroll
    for (int r = 0; r < 4; ++r) {
#pragma unroll
      for (int off = 1; off < 16; off <<= 1) nacc[r] += __shfl_xor(nacc[r], off, 64);
      irn[r] = rsqrtf(nacc[r]);
    }
  }
  unsigned short* nrm = (p == 0) ? qn_bf : kn_bf;
#pragma unroll
  for (int t = 0; t < 4; ++t) {
#pragma unroll
    for (int r = 0; r < 4; ++r) {
      int m = m0 + 16 * w + 4 * g + r;
      int bb = m >> 10, ii = m & 1023;
      dst[(((long long)(bb * 8 + h)) * 1024 + ii) * 64 + 16 * t + c] = ub[t][r];
      if (p < 2)
        nrm[(long long)m * 512 + n0 + 16 * t + c] = f2bf(bf2f(ub[t][r]) * irn[r]);
    }
  }
}

// ---------------- V transpose: vt[b,h,d,j] = v[b,h,j,d] ----------------
__global__ void transpose_v_kernel(const unsigned short* __restrict__ vbf,
                                   unsigned short* __restrict__ vt)
{
  __shared__ unsigned short ts[64][72];
  int bh = blockIdx.x, j0 = blockIdx.y * 64;
  int t = threadIdx.x;
  int jl = t >> 2, db = (t & 3) * 16;
  const unsigned short* src = vbf + ((long long)bh * 1024 + j0 + jl) * 64 + db;
  u16x8 v0 = *reinterpret_cast<const u16x8*>(src);
  u16x8 v1 = *reinterpret_cast<const u16x8*>(src + 8);
#pragma unroll
  for (int e = 0; e < 8; ++e) { ts[jl][db + e] = v0[e]; ts[jl][db + 8 + e] = v1[e]; }
  __syncthreads();
  int d = t >> 2, jb = (t & 3) * 16;
  u16x8 o0, o1;
#pragma unroll
  for (int e = 0; e < 8; ++e) { o0[e] = ts[jb + e][d]; o1[e] = ts[jb + 8 + e][d]; }
  unsigned short* dst = vt + ((long long)bh * 64 + d) * 1024 + j0 + jb;
  *reinterpret_cast<u16x8*>(dst) = o0;
  *reinterpret_cast<u16x8*>(dst + 8) = o1;
}

// ---------------- per-head attention: QK^T + softmax + attn store + PV ----------------
#define P_STRIDE 1044
__global__ __launch_bounds__(256, 4) void attn_head_kernel(
    const unsigned short* __restrict__ qbf, const unsigned short* __restrict__ kbf,
    const ull* __restrict__ bits, const unsigned short* __restrict__ vt,
    float* __restrict__ attn_out, unsigned short* __restrict__ inter)
{
  __shared__ unsigned short P_lds[16 * P_STRIDE];
  __shared__ float redM[4][16], redS[4][16];
  const int i0 = blockIdx.x * 16;
  const int bh = blockIdx.y;
  const int b = bh >> 3, h = bh & 7;
  const int w = threadIdx.x >> 6, L = threadIdx.x & 63, c = L & 15, g = L >> 4;
  const int j0 = 256 * w;
  const long long bho = (long long)bh * 65536;

  // Q fragments (rows i0+c, k = 8g / 8g+32)
  const unsigned short* qh = qbf + bho + (i0 + c) * 64 + 8 * g;
  bf8_t a0 = *reinterpret_cast<const bf8_t*>(qh);
  bf8_t a1 = *reinterpret_cast<const bf8_t*>(qh + 32);

  // mask words: bit for (r, jt) is (w64[r] >> (4*jt + (c>>2))) & 1
  ull w64[4];
  const int e = c & 3, csh = c >> 2;
#pragma unroll
  for (int r = 0; r < 4; ++r)
    w64[r] = bits[((long long)b * 1024 + i0 + 4 * g + r) * 16 + 4 * w + e];

  // QK^T scores
  f32x4 sc[16];
  const unsigned short* kh = kbf + bho + (long long)j0 * 64 + 8 * g;
#pragma unroll
  for (int jt = 0; jt < 16; ++jt) {
    const unsigned short* kp = kh + (16 * jt + c) * 64;
    f32x4 acc = {0.f, 0.f, 0.f, 0.f};
    acc = __builtin_amdgcn_mfma_f32_16x16x32_bf16(a0, *reinterpret_cast<const bf8_t*>(kp), acc, 0, 0, 0);
    acc = __builtin_amdgcn_mfma_f32_16x16x32_bf16(a1, *reinterpret_cast<const bf8_t*>(kp + 32), acc, 0, 0, 0);
    sc[jt] = acc;
  }

  // mask + scale + wave-local max
  float rmax[4] = {-1e30f, -1e30f, -1e30f, -1e30f};
#pragma unroll
  for (int jt = 0; jt < 16; ++jt) {
#pragma unroll
    for (int r = 0; r < 4; ++r) {
      float lg = ((w64[r] >> (4 * jt + csh)) & 1ull) ? sc[jt][r] * 0.125f
                                                     : -2.8782313662425572f; // LARGE_NEG/8
      sc[jt][r] = lg;
      rmax[r] = fmaxf(rmax[r], lg);
    }
  }
#pragma unroll
  for (int r = 0; r < 4; ++r) {
#pragma unroll
    for (int off = 1; off < 16; off <<= 1)
      rmax[r] = fmaxf(rmax[r], __shfl_xor(rmax[r], off, 64));
  }
  float rsum[4] = {0.f, 0.f, 0.f, 0.f};
#pragma unroll
  for (int jt = 0; jt < 16; ++jt) {
#pragma unroll
    for (int r = 0; r < 4; ++r) {
      float p = __expf(sc[jt][r] - rmax[r]);
      sc[jt][r] = p;
      rsum[r] += p;
    }
  }
#pragma unroll
  for (int r = 0; r < 4; ++r) {
#pragma unroll
    for (int off = 1; off < 16; off <<= 1) rsum[r] += __shfl_xor(rsum[r], off, 64);
  }
  if (c == 0) {
#pragma unroll
    for (int r = 0; r < 4; ++r) { redM[w][4 * g + r] = rmax[r]; redS[w][4 * g + r] = rsum[r]; }
  }
  __syncthreads();  // B1
  float scale[4];
#pragma unroll
  for (int r = 0; r < 4; ++r) {
    int row = 4 * g + r;
    float m0v = redM[0][row], m1v = redM[1][row], m2v = redM[2][row], m3v = redM[3][row];
    float M = fmaxf(fmaxf(m0v, m1v), fmaxf(m2v, m3v));
    float den = redS[0][row] * __expf(m0v - M) + redS[1][row] * __expf(m1v - M) +
                redS[2][row] * __expf(m2v - M) + redS[3][row] * __expf(m3v - M);
    scale[r] = __expf(rmax[r] - M) / den;
  }
#pragma unroll
  for (int jt = 0; jt < 16; ++jt) {
#pragma unroll
    for (int r = 0; r < 4; ++r)
      P_lds[(4 * g + r) * P_STRIDE + j0 + 16 * jt + c] = f2bf(sc[jt][r] * scale[r]);
  }
  __syncthreads();  // B2

  // PV: O[i 16 x d 16w+c] from P_lds rows (i=c) x vt rows (d)
  {
    const unsigned short* vp = vt + ((long long)bh * 64 + 16 * w + c) * 1024 + 8 * g;
    f32x4 oacc = {0.f, 0.f, 0.f, 0.f};
#pragma unroll 4
    for (int ks = 0; ks < 32; ++ks) {
      bf8_t pa = *reinterpret_cast<const bf8_t*>(P_lds + c * P_STRIDE + 32 * ks + 8 * g);
      bf8_t vb = *reinterpret_cast<const bf8_t*>(vp + 32 * ks);
      oacc = __builtin_amdgcn_mfma_f32_16x16x32_bf16(pa, vb, oacc, 0, 0, 0);
    }
#pragma unroll
    for (int r = 0; r < 4; ++r)
      inter[((long long)b * 1024 + i0 + 4 * g + r) * 512 + h * 64 + 16 * w + c] = f2bf(oacc[r]);
  }

  // coalesced attn f32 store from P_lds
  {
    float* ao = attn_out + ((long long)bh * 1024 + i0) * 1024;
#pragma unroll
    for (int rr = 0; rr < 4; ++rr) {
      int row = 4 * w + rr;
      const unsigned short* pr = P_lds + row * P_STRIDE;
      u16x8 h0 = *reinterpret_cast<const u16x8*>(pr + 8 * L);
      u16x8 h1 = *reinterpret_cast<const u16x8*>(pr + 512 + 8 * L);
      float* aorow = ao + (long long)row * 1024;
      f32x4 f0, f1, f2, f3;
#pragma unroll
      for (int q = 0; q < 4; ++q) {
        f0[q] = bf2f(h0[q]); f1[q] = bf2f(h0[4 + q]);
        f2[q] = bf2f(h1[q]); f3[q] = bf2f(h1[4 + q]);
      }
      *reinterpret_cast<f32x4*>(aorow + 8 * L) = f0;
      *reinterpret_cast<f32x4*>(aorow + 8 * L + 4) = f1;
      *reinterpret_cast<f32x4*>(aorow + 512 + 8 * L) = f2;
      *reinterpret_cast<f32x4*>(aorow + 512 + 8 * L + 4) = f3;
    }
  }
}

// ---------------- loss: cosine GEMM (qn.kn) + num/den + popcount regular ----------------
__global__ __launch_bounds__(512, 4) void loss_kernel(
    const unsigned short* __restrict__ qn, const unsigned short* __restrict__ kn,
    const ull* __restrict__ bits, float* __restrict__ partials)
{
  __shared__ float redN[8][16], redD[8][16], redP[8][16];
  const int i0 = blockIdx.x * 16;
  const int b = blockIdx.y;
  const int w = threadIdx.x >> 6, L = threadIdx.x & 63, c = L & 15, g = L >> 4;
  const int j0 = 128 * w;
  const long long rowbase = (long long)b * 1024;

  f32x4 acc[8];
#pragma unroll
  for (int jt = 0; jt < 8; ++jt) acc[jt] = f32x4{0.f, 0.f, 0.f, 0.f};
  const unsigned short* qp = qn + (rowbase + i0 + c) * 512 + 8 * g;
  const unsigned short* kp = kn + (rowbase + j0 + c) * 512 + 8 * g;
#pragma unroll 2
  for (int kc = 0; kc < 16; ++kc) {
    bf8_t a = *reinterpret_cast<const bf8_t*>(qp + 32 * kc);
#pragma unroll
    for (int jt = 0; jt < 8; ++jt) {
      bf8_t bb = *reinterpret_cast<const bf8_t*>(kp + (long long)(16 * jt) * 512 + 32 * kc);
      acc[jt] = __builtin_amdgcn_mfma_f32_16x16x32_bf16(a, bb, acc[jt], 0, 0, 0);
    }
  }

  // mask bits: j = 128w + 16jt + c -> word 4*(w>>1) + (c&3), bit 32*(w&1) + 4jt + (c>>2)
  const int e = c & 3, csh = c >> 2, half = (w & 1) * 32;
  ull w64[4];
#pragma unroll
  for (int r = 0; r < 4; ++r)
    w64[r] = bits[(rowbase + i0 + 4 * g + r) * 16 + 4 * (w >> 1) + e];

  float num[4] = {0.f, 0.f, 0.f, 0.f}, den[4] = {0.f, 0.f, 0.f, 0.f}, pcv[4];
#pragma unroll
  for (int r = 0; r < 4; ++r)
    pcv[r] = (c < 4) ? (float)__popcll((w64[r] >> half) & 0xFFFFFFFFull) : 0.f;
#pragma unroll
  for (int jt = 0; jt < 8; ++jt) {
#pragma unroll
    for (int r = 0; r < 4; ++r) {
      float ee = __expf(acc[jt][r] * 1.25f);
      den[r] += ee;
      num[r] += ((w64[r] >> (half + 4 * jt + csh)) & 1ull) ? ee : 0.f;
    }
  }
#pragma unroll
  for (int r = 0; r < 4; ++r) {
#pragma unroll
    for (int off = 1; off < 16; off <<= 1) {
      num[r] += __shfl_xor(num[r], off, 64);
      den[r] += __shfl_xor(den[r], off, 64);
      pcv[r] += __shfl_xor(pcv[r], off, 64);
    }
  }
  if (c == 0) {
#pragma unroll
    for (int r = 0; r < 4; ++r) {
      redN[w][4 * g + r] = num[r]; redD[w][4 * g + r] = den[r]; redP[w][4 * g + r] = pcv[r];
    }
  }
  __syncthreads();
  if (w == 0) {
    float cl = 0.f, rg = 0.f;
    if (L < 16) {
      float nm = 0.f, dn = 0.f, pc = 0.f;
#pragma unroll
      for (int ww = 0; ww < 8; ++ww) { nm += redN[ww][L]; dn += redD[ww][L]; pc += redP[ww][L]; }
      cl = __logf(dn) - __logf(nm);
      rg = pc - 1.0f;
    }
#pragma unroll
    for (int off = 1; off < 64; off <<= 1) { cl += __shfl_xor(cl, off, 64); rg += __shfl_xor(rg, off, 64); }
    if (L == 0)
      partials[blockIdx.y * 64 + blockIdx.x] = cl * (1.0f / 8192.0f) + rg * (float)(0.3 / 8380416.0);
  }
}

// ---------------- out-proj GEMM: out[8192,512] = inter @ wo^T + bo (fp32 out) ----------------
__global__ __launch_bounds__(256) void outproj_gemm_kernel(
    const unsigned short* __restrict__ A, const unsigned short* __restrict__ W,
    const float* __restrict__ bias, float* __restrict__ out_f32)
{
  const int m0 = blockIdx.x * 64;
  const int n0 = blockIdx.y * 64;
  const int w = threadIdx.x >> 6, L = threadIdx.x & 63, c = L & 15, g = L >> 4;
  const unsigned short* arow = A + (long long)(m0 + 16 * w + c) * 512 + 8 * g;
  const unsigned short* wrow = W + (long long)(n0 + c) * 512 + 8 * g;
  f32x4 acc0 = {0.f, 0.f, 0.f, 0.f}, acc1 = acc0, acc2 = acc0, acc3 = acc0;
#pragma unroll 4
  for (int kk = 0; kk < 16; ++kk) {
    bf8_t a  = *reinterpret_cast<const bf8_t*>(arow + 32 * kk);
    bf8_t b0 = *reinterpret_cast<const bf8_t*>(wrow + 32 * kk);
    bf8_t b1 = *reinterpret_cast<const bf8_t*>(wrow + 16 * 512 + 32 * kk);
    bf8_t b2 = *reinterpret_cast<const bf8_t*>(wrow + 32 * 512 + 32 * kk);
    bf8_t b3 = *reinterpret_cast<const bf8_t*>(wrow + 48 * 512 + 32 * kk);
    acc0 = __builtin_amdgcn_mfma_f32_16x16x32_bf16(a, b0, acc0, 0, 0, 0);
    acc1 = __builtin_amdgcn_mfma_f32_16x16x32_bf16(a, b1, acc1, 0, 0, 0);
    acc2 = __builtin_amdgcn_mfma_f32_16x16x32_bf16(a, b2, acc2, 0, 0, 0);
    acc3 = __builtin_amdgcn_mfma_f32_16x16x32_bf16(a, b3, acc3, 0, 0, 0);
  }
  f32x4 accs[4] = {acc0, acc1, acc2, acc3};
#pragma unroll
  for (int t = 0; t < 4; ++t) {
    int n = n0 + 16 * t + c;
    float bv = bias[n];
#pragma unroll
    for (int r = 0; r < 4; ++r)
      out_f32[(long long)(m0 + 16 * w + 4 * g + r) * 512 + n] = accs[t][r] + bv;
  }
}

// ---------------- deterministic loss reduction ----------------
__global__ void loss_reduce_kernel(const float* __restrict__ partials, float* __restrict__ out) {
  int t = threadIdx.x;
  float s = partials[t] + partials[t + 256];
#pragma unroll
  for (int off = 1; off < 64; off <<= 1) s += __shfl_xor(s, off, 64);
  __shared__ float red[4];
  if ((t & 63) == 0) red[t >> 6] = s;
  __syncthreads();
  if (t == 0) out[0] = red[0] + red[1] + red[2] + red[3];
}

extern "C" void kernel_launch(void* const* d_in, const int* in_sizes, int n_in,
                              void* d_out, int out_size, void* d_ws, size_t ws_size,
                              hipStream_t stream)
{
  const float* x    = (const float*)d_in[0];
  const float* mask = (const float*)d_in[1];
  const float* wq = (const float*)d_in[2]; const float* bq = (const float*)d_in[3];
  const float* wk = (const float*)d_in[4]; const float* bk = (const float*)d_in[5];
  const float* wv = (const float*)d_in[6]; const float* bv = (const float*)d_in[7];
  const float* wo = (const float*)d_in[8]; const float* bo = (const float*)d_in[9];

  unsigned short* x_bf  = (unsigned short*)d_ws;          // 4.19M ush; reused as inter later
  unsigned short* wq_bf = x_bf + 4194304;
  unsigned short* wk_bf = wq_bf + 262144;
  unsigned short* wv_bf = wk_bf + 262144;
  unsigned short* wo_bf = wv_bf + 262144;
  unsigned short* q_bf  = wo_bf + 262144;
  unsigned short* k_bf  = q_bf + 4194304;
  unsigned short* v_bf  = k_bf + 4194304;
  unsigned short* vt_bf = v_bf + 4194304;
  unsigned short* qn_bf = vt_bf + 4194304;
  unsigned short* kn_bf = qn_bf + 4194304;
  ull* bits    = (ull*)(kn_bf + 4194304);                 // 131072 u64 = 1 MB
  float* parts = (float*)(bits + 131072);                 // 512 f32
  unsigned short* inter = x_bf;                           // reuse (x_bf dead after qkv)

  float* out_f  = (float*)d_out;
  float* attn_o = out_f + 4194304;
  float* loss_o = attn_o + 67108864;

  cvt_kernel<<<4096, 256, 0, stream>>>(x, x_bf, 1048576);
  cvt_kernel<<<256, 256, 0, stream>>>(wq, wq_bf, 65536);
  cvt_kernel<<<256, 256, 0, stream>>>(wk, wk_bf, 65536);
  cvt_kernel<<<256, 256, 0, stream>>>(wv, wv_bf, 65536);
  cvt_kernel<<<256, 256, 0, stream>>>(wo, wo_bf, 65536);

  maskpack_kernel<<<2048, 256, 0, stream>>>(mask, bits);

  qkv_gemm_kernel<<<dim3(128, 24), 256, 0, stream>>>(
      x_bf, wq_bf, wk_bf, wv_bf, bq, bk, bv, q_bf, k_bf, v_bf, qn_bf, kn_bf);

  transpose_v_kernel<<<dim3(64, 16), 256, 0, stream>>>(v_bf, vt_bf);

  loss_kernel<<<dim3(64, 8), 512, 0, stream>>>(qn_bf, kn_bf, bits, parts);

  attn_head_kernel<<<dim3(64, 64), 256, 0, stream>>>(
      q_bf, k_bf, bits, vt_bf, attn_o, inter);

  outproj_gemm_kernel<<<dim3(128, 8), 256, 0, stream>>>(inter, wo_bf, bo, out_f);

  loss_reduce_kernel<<<1, 256, 0, stream>>>(parts, loss_o);
}